// Round 22
// baseline (55.112 us; speedup 1.0000x reference)
//
#include <hip/hip_runtime.h>
#include <hip/hip_bf16.h>
#include <stdint.h>

#define NPTS 4096
#define NNBR 16      // neighbors kept (reference keeps 17 incl. self, drops self)
#define PPB  16      // points per block
#define NSEG 32      // coarse segments for scan2 (seg = t>>4); 64 cands/half
#define HALF 2048    // points staged per half
#define HSEGLEN 64   // candidates per coarse segment per half
#define SEGPAD 68    // 68 % 32 == 4: wave's seg-rows land on distinct bank-quads
#define HSTR 65      // heads stride per point (64 fine-seg minima + pad)
#define CAP  96      // accepted capacity (tau rank ~19.5, headroom ~4x)
#define TAUM 1.0e-3f // proxy-vs-pinned margin (bound ~5e-5; 20x safety)
#define BIGD 3.4e38f

// ---------------------------------------------------------------------------
// PINNED distance (numpy-order, no contraction) — extraction only; bitwise
// stable accepted-list d2 => stable 16-NN sets.
// ---------------------------------------------------------------------------
__device__ __forceinline__ float sqnorm(float x, float y, float z) {
    return __fadd_rn(__fadd_rn(__fmul_rn(x, x), __fmul_rn(y, y)), __fmul_rn(z, z));
}
__device__ __forceinline__ float d2r(float px, float py, float pz, float sqp,
                                     float cx, float cy, float cz) {
    const float sqq = sqnorm(cx, cy, cz);
    const float dot = __fadd_rn(__fadd_rn(__fmul_rn(px, cx), __fmul_rn(py, cy)),
                                __fmul_rn(pz, cz));
    return __fsub_rn(__fadd_rn(sqp, sqq), __fadd_rn(dot, dot));
}
// CHEAP proxy pieces. sqf+edot compose to EXACTLY eproxy2's instruction
// sequence -> identical e bits whether sqq is shared (scan1) or not (scan2).
__device__ __forceinline__ float sqf(float cx, float cy, float cz) {
    return __builtin_fmaf(cz, cz, __builtin_fmaf(cy, cy, __fmul_rn(cx, cx)));
}
__device__ __forceinline__ float edot(float px, float py, float pz,
                                      float cx, float cy, float cz, float sqq) {
    const float dot = __builtin_fmaf(px, cx, __builtin_fmaf(py, cy, __fmul_rn(pz, cz)));
    return __builtin_fmaf(dot, -2.0f, sqq);
}
__device__ __forceinline__ float eproxy2(float px, float py, float pz,
                                         float cx, float cy, float cz) {
    return edot(px, py, pz, cx, cy, cz, sqf(cx, cy, cz));
}

// generic K-deep min/max ladder over a register array (static unroll only)
#define LADK(AD, K, S)                                            \
    _Pragma("unroll")                                             \
    for (int k_ = 0; k_ < (K); ++k_) {                            \
        const float lo_ = fminf((S), AD[k_]);                     \
        (S) = fmaxf((S), AD[k_]);                                 \
        AD[k_] = lo_;                                             \
    }

// ---------------------------------------------------------------------------
// FULLY FUSED: exact 16-NN + per-edge MLP + neighbor mean + v0 copy.
// R21 (proven 53.0us total, absmax 0.0546875) with ONE delta:
// scan1 remapped to 2 POINTS/THREAD on 64 fine segments (32 cands/half each):
//   - 3 float4 reads feed 8 point-candidate evals (48 b128/thread in scan1
//     vs 96; kernel total 192 -> 144, -25% LDS-pipe)
//   - sqq computed once per candidate serves both points (-15% scan1 VALU)
//   - lean state (6 coord regs + 4 min chains) stays far below the R8/R12
//     multi-point spill threshold (no masks/extraction per point)
//   - tau = 17th of 64 fine-seg minima: still a valid subset order-stat
//     bound (64 distinct real e-values >= 17) and TIGHTER (coupon-collector
//     rank ~19.5 vs 23) -> accepted ~20, smaller tail.
// scan2 / extraction / rank-select / MLP phases byte-identical to R21.
// ---------------------------------------------------------------------------
__global__ __launch_bounds__(512, 8) void fused_kernel(const float* __restrict__ x0,
                                                       const float* __restrict__ v0,
                                                       const float* __restrict__ W,
                                                       const float* __restrict__ bias,
                                                       float* __restrict__ out) {
    __shared__ float sx[NSEG * SEGPAD], sy[NSEG * SEGPAD],
                     sz[NSEG * SEGPAD];                      // 3 x 8,704 B
    __shared__ float2 list[PPB * CAP];                       // 12,288 B
    __shared__ ushort nbrL[PPB][NNBR];                       // 512 B
    __shared__ float ttau[PPB];
    __shared__ int   cnt[PPB];

    float* heads = (float*)list;             // alias: dead before extraction
    float* nbf   = (float*)list;             // alias: dead after rank phase

    const int b     = blockIdx.x >> 8;       // 256 chunks per batch
    const int chunk = blockIdx.x & 255;
    const float* Xb = x0 + b * (NPTS * 3);
    const float* Vb = v0 + b * (NPTS * 3);
    const int t = threadIdx.x;

    // ---- folded v0 passthrough: first 24 blocks copy one float4/thread ----
    {
        const int gid = blockIdx.x * 512 + t;
        if (gid < (4 * NPTS * 3) / 4)
            ((float4*)(out + 4 * NPTS * 64))[gid] = ((const float4*)v0)[gid];
    }

    // scan2 mapping (unchanged from R21)
    const int pt = t & 15, seg = t >> 4;     // coarse seg 0..31
    const int p  = chunk * PPB + pt;         // batch-local point id
    const float px = Xb[3 * p + 0];
    const float py = Xb[3 * p + 1];
    const float pz = Xb[3 * p + 2];
    const float sqp = sqnorm(px, py, pz);
    const int sb = seg * SEGPAD;

    // scan1 mapping: 8 point-pairs x 64 fine segments (32 cands/half each)
    const int u2 = t & 7;                    // pair 0..7
    const int sg = t >> 3;                   // fine seg 0..63
    const int pA = chunk * PPB + 2 * u2;
    const int pB = pA + 1;
    const float pxA = Xb[3 * pA + 0], pyA = Xb[3 * pA + 1], pzA = Xb[3 * pA + 2];
    const float pxB = Xb[3 * pB + 0], pyB = Xb[3 * pB + 1], pzB = Xb[3 * pB + 2];
    const int sb2 = (sg >> 1) * SEGPAD + (sg & 1) * 32;

    // stage one 2048-point half into LDS (4 pts/thread, 3 arrays)
#define STAGE(HB)                                                  \
    for (int i = t; i < HALF; i += 512) {                          \
        const int g = (HB) * HALF + i;                             \
        const int a = (i >> 6) * SEGPAD + (i & 63);                \
        sx[a] = Xb[3 * g + 0];                                     \
        sy[a] = Xb[3 * g + 1];                                     \
        sz[a] = Xb[3 * g + 2];                                     \
    }

    // per-half 2-point min-chains over this thread's 32 candidates
#define SCAN1H2()                                                  \
    for (int j = 0; j < 8; j += 2) {                               \
        const int oa = sb2 + 4 * j;                                \
        const int ob = oa + 4;                                     \
        const float4 cxa = *(const float4*)&sx[oa];                \
        const float4 cya = *(const float4*)&sy[oa];                \
        const float4 cza = *(const float4*)&sz[oa];                \
        const float4 cxb = *(const float4*)&sx[ob];                \
        const float4 cyb = *(const float4*)&sy[ob];                \
        const float4 czb = *(const float4*)&sz[ob];                \
        const float wa0 = sqf(cxa.x, cya.x, cza.x);                \
        const float wa1 = sqf(cxa.y, cya.y, cza.y);                \
        const float wa2 = sqf(cxa.z, cya.z, cza.z);                \
        const float wa3 = sqf(cxa.w, cya.w, cza.w);                \
        const float wb0 = sqf(cxb.x, cyb.x, czb.x);                \
        const float wb1 = sqf(cxb.y, cyb.y, czb.y);                \
        const float wb2 = sqf(cxb.z, cyb.z, czb.z);                \
        const float wb3 = sqf(cxb.w, cyb.w, czb.w);                \
        cA0 = fminf(cA0, fminf(                                    \
            fminf(edot(pxA, pyA, pzA, cxa.x, cya.x, cza.x, wa0),   \
                  edot(pxA, pyA, pzA, cxa.y, cya.y, cza.y, wa1)),  \
            fminf(edot(pxA, pyA, pzA, cxa.z, cya.z, cza.z, wa2),   \
                  edot(pxA, pyA, pzA, cxa.w, cya.w, cza.w, wa3)))); \
        cA1 = fminf(cA1, fminf(                                    \
            fminf(edot(pxA, pyA, pzA, cxb.x, cyb.x, czb.x, wb0),   \
                  edot(pxA, pyA, pzA, cxb.y, cyb.y, czb.y, wb1)),  \
            fminf(edot(pxA, pyA, pzA, cxb.z, cyb.z, czb.z, wb2),   \
                  edot(pxA, pyA, pzA, cxb.w, cyb.w, czb.w, wb3)))); \
        cB0 = fminf(cB0, fminf(                                    \
            fminf(edot(pxB, pyB, pzB, cxa.x, cya.x, cza.x, wa0),   \
                  edot(pxB, pyB, pzB, cxa.y, cya.y, cza.y, wa1)),  \
            fminf(edot(pxB, pyB, pzB, cxa.z, cya.z, cza.z, wa2),   \
                  edot(pxB, pyB, pzB, cxa.w, cya.w, cza.w, wa3)))); \
        cB1 = fminf(cB1, fminf(                                    \
            fminf(edot(pxB, pyB, pzB, cxb.x, cyb.x, czb.x, wb0),   \
                  edot(pxB, pyB, pzB, cxb.y, cyb.y, czb.y, wb1)),  \
            fminf(edot(pxB, pyB, pzB, cxb.z, cyb.z, czb.z, wb2),   \
                  edot(pxB, pyB, pzB, cxb.w, cyb.w, czb.w, wb3)))); \
    }

    // per-half scan2: bitmask accept + extraction with PINNED d2 (unchanged)
#define SCAN2H(HB)                                                             \
    for (int w = 0; w < 2; ++w) {                                              \
        uint m = 0;                                                            \
        _Pragma("unroll")                                                      \
        for (int jj = 0; jj < 8; ++jj) {                                       \
            const int o = sb + w * 32 + 4 * jj;                                \
            const float4 cx4 = *(const float4*)&sx[o];                         \
            const float4 cy4 = *(const float4*)&sy[o];                         \
            const float4 cz4 = *(const float4*)&sz[o];                         \
            const float s0 = eproxy2(px, py, pz, cx4.x, cy4.x, cz4.x);         \
            const float s1 = eproxy2(px, py, pz, cx4.y, cy4.y, cz4.y);         \
            const float s2 = eproxy2(px, py, pz, cx4.z, cy4.z, cz4.z);         \
            const float s3 = eproxy2(px, py, pz, cx4.w, cy4.w, cz4.w);         \
            m |= (s0 <= tv) ? (1u << (4 * jj + 0)) : 0u;                       \
            m |= (s1 <= tv) ? (1u << (4 * jj + 1)) : 0u;                       \
            m |= (s2 <= tv) ? (1u << (4 * jj + 2)) : 0u;                       \
            m |= (s3 <= tv) ? (1u << (4 * jj + 3)) : 0u;                       \
        }                                                                      \
        while (m) {                                                            \
            const int bpos = __ffs(m) - 1;                                     \
            m &= m - 1;                                                        \
            const int l = seg * HSEGLEN + w * 32 + bpos;                       \
            const int q = (HB) * HALF + l;   /* batch-local cand id */         \
            if (q != p) {                                                      \
                const int qa = (l >> 6) * SEGPAD + (l & 63);                   \
                const float d2 = d2r(px, py, pz, sqp, sx[qa], sy[qa], sz[qa]); \
                const int o2 = atomicAdd(&cnt[pt], 1);                         \
                if (o2 < CAP) list[pt * CAP + o2] = make_float2(d2, __int_as_float(q)); \
            }                                                                  \
        }                                                                      \
    }

    // ---- phase A: stage half0, 2-pt scan1 on it ----
    STAGE(0)
    if (t < PPB) cnt[t] = 0;
    __syncthreads();

    float cA0 = BIGD, cA1 = BIGD, cB0 = BIGD, cB1 = BIGD;
    SCAN1H2()
    __syncthreads();                         // done reading half0

    // ---- phase B: stage half1, finish scan1, write fine-seg minima ----
    STAGE(1)
    __syncthreads();
    SCAN1H2()
    heads[(2 * u2 + 0) * HSTR + sg] = fminf(cA0, cA1);
    heads[(2 * u2 + 1) * HSTR + sg] = fminf(cB0, cB1);
    __syncthreads();

    // ---- tau: 1 thr/pt, LAD17 over the 64 fine-seg minima (rotated) ----
    if (t < PPB) {
        float ad[17];
#pragma unroll
        for (int k = 0; k < 17; ++k) ad[k] = BIGD;
        const float* src = heads + t * HSTR;
        for (int e = 0; e < 64; ++e) {
            float s = src[(e + t) & 63];
            LADK(ad, 17, s)
        }
        ttau[t] = ad[16];                    // 17th-smallest seg-minimum
    }
    __syncthreads();                         // heads dead; list reuses the space

    // ---- phase C: scan2 on resident half1, then restage half0 and scan2 ----
    const float tv = ttau[pt] + TAUM;
    SCAN2H(1)
    __syncthreads();                         // done reading half1
    STAGE(0)
    __syncthreads();
    SCAN2H(0)
    __syncthreads();

    // ---- rank-by-counting select -> LDS neighbor table (ranks 0..15) ----
    {
        const int p2 = t >> 5;               // point 0..15
        const int sl = t & 31;               // slot 0..31
        const int n  = min(cnt[p2], CAP);    // always >= 16 (tau >= e_(17))
        for (int e = sl; e < n; e += 32) {
            const float2 ve = list[p2 * CAP + e];
            const int ie = __float_as_int(ve.y);
            int r = 0;
            for (int f = 0; f < n; ++f) {
                const float2 vf = list[p2 * CAP + f];
                const bool lt = (vf.x < ve.x) ||
                                (vf.x == ve.x && __float_as_int(vf.y) < ie);
                r += lt ? 1 : 0;
            }
            if (r < NNBR) nbrL[p2][r] = (ushort)ie;
        }
    }
    __syncthreads();                         // list dead; nbf reuses the space

    // ---- fused MLP stage: 256 threads gather neighbor Xj/Vj (6 floats) ----
    if (t < 256) {
        const int p2 = t >> 4, nn = t & 15;
        const int j  = (int)nbrL[p2][nn];
        float* dst = nbf + (p2 * NNBR + nn) * 6;
        dst[0] = Xb[3 * j + 0];
        dst[1] = Xb[3 * j + 1];
        dst[2] = Xb[3 * j + 2];
        dst[3] = Vb[3 * j + 0];
        dst[4] = Vb[3 * j + 1];
        dst[5] = Vb[3 * j + 2];
    }
    __syncthreads();

    // ---- fused MLP compute: 8 waves x 64 channels, 2 points per wave ----
    {
        const int lane = t & 63;
        const int wv   = t >> 6;             // 0..7
        float w[12];
#pragma unroll
        for (int k = 0; k < 12; ++k) w[k] = W[k * 64 + lane];
        const float bb = bias[lane];

#pragma unroll
        for (int pp = 0; pp < 2; ++pp) {
            const int pi = wv + 8 * pp;      // point 0..15
            const int pg = chunk * PPB + pi; // batch-local point id
            const float xi0 = Xb[pg * 3 + 0], xi1 = Xb[pg * 3 + 1], xi2 = Xb[pg * 3 + 2];
            const float vi0 = Vb[pg * 3 + 0], vi1 = Vb[pg * 3 + 1], vi2 = Vb[pg * 3 + 2];
            const float base = bb + w[0] * xi0 + w[1] * xi1 + w[2] * xi2
                                  + w[6] * vi0 + w[7] * vi1 + w[8] * vi2;
            float acc = 0.0f;
#pragma unroll
            for (int n = 0; n < NNBR; ++n) {
                const float* f = nbf + (pi * NNBR + n) * 6;
                const float h = base + w[3]  * f[0] + w[4]  * f[1]
                                     + w[5]  * f[2] + w[9]  * f[3]
                                     + w[10] * f[4] + w[11] * f[5];
                acc += fmaxf(h, 0.0f);
            }
            out[(size_t)(b * NPTS + pg) * 64 + lane] = acc * (1.0f / 16.0f);
        }
    }
#undef STAGE
#undef SCAN1H2
#undef SCAN2H
}

extern "C" void kernel_launch(void* const* d_in, const int* in_sizes, int n_in,
                              void* d_out, int out_size, void* d_ws, size_t ws_size,
                              hipStream_t stream) {
    const float* x0 = (const float*)d_in[0];   // (4, 12288)
    const float* v0 = (const float*)d_in[1];   // (4, 12288)
    const float* W  = (const float*)d_in[2];   // (12, 64)
    const float* bb = (const float*)d_in[3];   // (64,)
    float* out = (float*)d_out;

    // Single fused dispatch: 16-NN + MLP + mean + v0 copy.
    // 1024 blocks (4 batches x 256 chunks of 16 points), 512 threads.
    fused_kernel<<<1024, 512, 0, stream>>>(x0, v0, W, bb, out);
}

// Round 23
// 53.027 us; speedup vs baseline: 1.0393x; 1.0393x over previous
//
#include <hip/hip_runtime.h>
#include <hip/hip_bf16.h>
#include <stdint.h>

#define NPTS 4096
#define NNBR 16      // neighbors kept (reference keeps 17 incl. self, drops self)
#define PPB  16      // points per block
#define NSEG 32      // segments (seg = t>>4); 64 cands per half-segment
#define HALF 2048    // points staged per half
#define HSEGLEN 64   // candidates per segment per half
#define SEGPAD 68    // 68 % 32 == 4: wave's 4 seg-rows land on distinct bank-quads
#define HSTR 33      // heads stride per point (32 seg-minima + pad)
#define CAP  96      // accepted capacity (full-statistic tau: rank ~23, proven)
#define TAUM 1.0e-3f // proxy-vs-pinned margin (bound ~5e-5; 20x safety)
#define BIGD 3.4e38f

// ---------------------------------------------------------------------------
// PINNED distance (numpy-order, no contraction) — extraction only; bitwise
// stable accepted-list d2 => stable 16-NN sets.
// ---------------------------------------------------------------------------
__device__ __forceinline__ float sqnorm(float x, float y, float z) {
    return __fadd_rn(__fadd_rn(__fmul_rn(x, x), __fmul_rn(y, y)), __fmul_rn(z, z));
}
__device__ __forceinline__ float d2r(float px, float py, float pz, float sqp,
                                     float cx, float cy, float cz) {
    const float sqq = sqnorm(cx, cy, cz);
    const float dot = __fadd_rn(__fadd_rn(__fmul_rn(px, cx), __fmul_rn(py, cy)),
                                __fmul_rn(pz, cz));
    return __fsub_rn(__fadd_rn(sqp, sqq), __fadd_rn(dot, dot));
}
// CHEAP proxy for the scans (7 VALU, sqq in-register). One macro for both
// scans -> identical bits per candidate; TAUM covers proxy-vs-pinned delta.
__device__ __forceinline__ float eproxy2(float px, float py, float pz,
                                         float cx, float cy, float cz) {
    const float sqq = __builtin_fmaf(cz, cz, __builtin_fmaf(cy, cy, __fmul_rn(cx, cx)));
    const float dot = __builtin_fmaf(px, cx, __builtin_fmaf(py, cy, __fmul_rn(pz, cz)));
    return __builtin_fmaf(dot, -2.0f, sqq);
}

// generic K-deep min/max ladder over a register array (static unroll only)
#define LADK(AD, K, S)                                            \
    _Pragma("unroll")                                             \
    for (int k_ = 0; k_ < (K); ++k_) {                            \
        const float lo_ = fminf((S), AD[k_]);                     \
        (S) = fmaxf((S), AD[k_]);                                 \
        AD[k_] = lo_;                                             \
    }

// ---------------------------------------------------------------------------
// FULLY FUSED: exact 16-NN + per-edge MLP + neighbor mean + v0 copy.
// Block = 512 thr = 16 points x 32 segments, grid = 1024 (1 pt/thread).
// kNN part identical to R19/R20 (proven, absmax 0.0546875):
//   half-staged (4 blocks/CU), min-only scan1, full-statistic tau (rank~23),
//   bitmask scan2 + pinned-d2 extraction, rank-by-counting select.
// Rank writes go to LDS nbrL[16][16] (every rank 0..15 hit exactly once
// since accepted>=16); after a barrier the block stages its 256 neighbors'
// Xj/Vj into the dead list region and runs the mlp math VERBATIM
// (8 waves x 64 ch x 2 pts), writing out directly. v0 copy folds into the
// first 24 blocks. One dispatch total — no nbr round-trip through HBM.
// Session plateau note: occupancy (R17), LDS-diet (R19/R22), latency-hiding
// (R20), single-scan (R15), multi-point (R8/R12) all explored; this is the
// best verified configuration (53.0us, R21).
// ---------------------------------------------------------------------------
__global__ __launch_bounds__(512, 8) void fused_kernel(const float* __restrict__ x0,
                                                       const float* __restrict__ v0,
                                                       const float* __restrict__ W,
                                                       const float* __restrict__ bias,
                                                       float* __restrict__ out) {
    __shared__ float sx[NSEG * SEGPAD], sy[NSEG * SEGPAD],
                     sz[NSEG * SEGPAD];                      // 3 x 8,704 B
    __shared__ float2 list[PPB * CAP];                       // 12,288 B
    __shared__ ushort nbrL[PPB][NNBR];                       // 512 B
    __shared__ float ttau[PPB];
    __shared__ int   cnt[PPB];

    float* heads = (float*)list;             // alias: dead before extraction
    float* nbf   = (float*)list;             // alias: dead after rank phase

    const int b     = blockIdx.x >> 8;       // 256 chunks per batch
    const int chunk = blockIdx.x & 255;
    const float* Xb = x0 + b * (NPTS * 3);
    const float* Vb = v0 + b * (NPTS * 3);
    const int t = threadIdx.x;

    // ---- folded v0 passthrough: first 24 blocks copy one float4/thread ----
    {
        const int gid = blockIdx.x * 512 + t;
        if (gid < (4 * NPTS * 3) / 4)
            ((float4*)(out + 4 * NPTS * 64))[gid] = ((const float4*)v0)[gid];
    }

    const int pt = t & 15, seg = t >> 4;     // seg 0..31
    const int p  = chunk * PPB + pt;         // batch-local point id
    const float px = Xb[3 * p + 0];          // own coords from GLOBAL
    const float py = Xb[3 * p + 1];          // (same f32 bits as staged)
    const float pz = Xb[3 * p + 2];
    const float sqp = sqnorm(px, py, pz);
    const int sb = seg * SEGPAD;

    // stage one 2048-point half into LDS (4 pts/thread, 3 arrays)
#define STAGE(HB)                                                  \
    for (int i = t; i < HALF; i += 512) {                          \
        const int g = (HB) * HALF + i;                             \
        const int a = (i >> 6) * SEGPAD + (i & 63);                \
        sx[a] = Xb[3 * g + 0];                                     \
        sy[a] = Xb[3 * g + 1];                                     \
        sz[a] = Xb[3 * g + 2];                                     \
    }

    // per-half min-chain over this thread's 64 candidates (dual chains)
#define SCAN1H(HA, HBCH)                                           \
    for (int j = 0; j < 16; j += 2) {                              \
        const int oa = sb + 4 * j;                                 \
        const int ob = oa + 4;                                     \
        const float4 cxa = *(const float4*)&sx[oa];                \
        const float4 cya = *(const float4*)&sy[oa];                \
        const float4 cza = *(const float4*)&sz[oa];                \
        const float4 cxb = *(const float4*)&sx[ob];                \
        const float4 cyb = *(const float4*)&sy[ob];                \
        const float4 czb = *(const float4*)&sz[ob];                \
        const float sa0 = eproxy2(px, py, pz, cxa.x, cya.x, cza.x); \
        const float sa1 = eproxy2(px, py, pz, cxa.y, cya.y, cza.y); \
        const float sa2 = eproxy2(px, py, pz, cxa.z, cya.z, cza.z); \
        const float sa3 = eproxy2(px, py, pz, cxa.w, cya.w, cza.w); \
        const float sb0 = eproxy2(px, py, pz, cxb.x, cyb.x, czb.x); \
        const float sb1 = eproxy2(px, py, pz, cxb.y, cyb.y, czb.y); \
        const float sb2 = eproxy2(px, py, pz, cxb.z, cyb.z, czb.z); \
        const float sb3 = eproxy2(px, py, pz, cxb.w, cyb.w, czb.w); \
        HA   = fminf(HA,   fminf(fminf(sa0, sa1), fminf(sa2, sa3))); \
        HBCH = fminf(HBCH, fminf(fminf(sb0, sb1), fminf(sb2, sb3))); \
    }

    // per-half scan2: bitmask accept + extraction with PINNED d2
#define SCAN2H(HB)                                                             \
    for (int w = 0; w < 2; ++w) {                                              \
        uint m = 0;                                                            \
        _Pragma("unroll")                                                      \
        for (int jj = 0; jj < 8; ++jj) {                                       \
            const int o = sb + w * 32 + 4 * jj;                                \
            const float4 cx4 = *(const float4*)&sx[o];                         \
            const float4 cy4 = *(const float4*)&sy[o];                         \
            const float4 cz4 = *(const float4*)&sz[o];                         \
            const float s0 = eproxy2(px, py, pz, cx4.x, cy4.x, cz4.x);         \
            const float s1 = eproxy2(px, py, pz, cx4.y, cy4.y, cz4.y);         \
            const float s2 = eproxy2(px, py, pz, cx4.z, cy4.z, cz4.z);         \
            const float s3 = eproxy2(px, py, pz, cx4.w, cy4.w, cz4.w);         \
            m |= (s0 <= tv) ? (1u << (4 * jj + 0)) : 0u;                       \
            m |= (s1 <= tv) ? (1u << (4 * jj + 1)) : 0u;                       \
            m |= (s2 <= tv) ? (1u << (4 * jj + 2)) : 0u;                       \
            m |= (s3 <= tv) ? (1u << (4 * jj + 3)) : 0u;                       \
        }                                                                      \
        while (m) {                                                            \
            const int bpos = __ffs(m) - 1;                                     \
            m &= m - 1;                                                        \
            const int l = seg * HSEGLEN + w * 32 + bpos;                       \
            const int q = (HB) * HALF + l;   /* batch-local cand id */         \
            if (q != p) {                                                      \
                const int qa = (l >> 6) * SEGPAD + (l & 63);                   \
                const float d2 = d2r(px, py, pz, sqp, sx[qa], sy[qa], sz[qa]); \
                const int o2 = atomicAdd(&cnt[pt], 1);                         \
                if (o2 < CAP) list[pt * CAP + o2] = make_float2(d2, __int_as_float(q)); \
            }                                                                  \
        }                                                                      \
    }

    // ---- phase A: stage half0, scan1 on it ----
    STAGE(0)
    if (t < PPB) cnt[t] = 0;
    __syncthreads();

    float ha = BIGD, hb = BIGD;
    SCAN1H(ha, hb)
    __syncthreads();                         // done reading half0

    // ---- phase B: stage half1, finish scan1, write seg-minima ----
    STAGE(1)
    __syncthreads();
    SCAN1H(ha, hb)
    heads[pt * HSTR + seg] = fminf(ha, hb);  // min over all 128 cands
    __syncthreads();

    // ---- tau: 1 thr/pt, LAD17 over the 32 seg-minima (rotated reads) ----
    if (t < PPB) {
        float ad[17];
#pragma unroll
        for (int k = 0; k < 17; ++k) ad[k] = BIGD;
        const float* src = heads + t * HSTR;
        for (int e = 0; e < 32; ++e) {
            float s = src[(e + t) & 31];
            LADK(ad, 17, s)
        }
        ttau[t] = ad[16];                    // 17th-smallest seg-minimum
    }
    __syncthreads();                         // heads dead; list reuses the space

    // ---- phase C: scan2 on resident half1, then restage half0 and scan2 ----
    const float tv = ttau[pt] + TAUM;
    SCAN2H(1)
    __syncthreads();                         // done reading half1
    STAGE(0)
    __syncthreads();
    SCAN2H(0)
    __syncthreads();

    // ---- rank-by-counting select -> LDS neighbor table (ranks 0..15) ----
    {
        const int p2 = t >> 5;               // point 0..15
        const int sl = t & 31;               // slot 0..31
        const int n  = min(cnt[p2], CAP);    // always >= 16 (tau >= e_(17))
        for (int e = sl; e < n; e += 32) {
            const float2 ve = list[p2 * CAP + e];
            const int ie = __float_as_int(ve.y);
            int r = 0;
            for (int f = 0; f < n; ++f) {
                const float2 vf = list[p2 * CAP + f];
                const bool lt = (vf.x < ve.x) ||
                                (vf.x == ve.x && __float_as_int(vf.y) < ie);
                r += lt ? 1 : 0;
            }
            if (r < NNBR) nbrL[p2][r] = (ushort)ie;
        }
    }
    __syncthreads();                         // list dead; nbf reuses the space

    // ---- fused MLP stage: 256 threads gather neighbor Xj/Vj (6 floats) ----
    if (t < 256) {
        const int p2 = t >> 4, nn = t & 15;
        const int j  = (int)nbrL[p2][nn];
        float* dst = nbf + (p2 * NNBR + nn) * 6;
        dst[0] = Xb[3 * j + 0];
        dst[1] = Xb[3 * j + 1];
        dst[2] = Xb[3 * j + 2];
        dst[3] = Vb[3 * j + 0];
        dst[4] = Vb[3 * j + 1];
        dst[5] = Vb[3 * j + 2];
    }
    __syncthreads();

    // ---- fused MLP compute: 8 waves x 64 channels, 2 points per wave ----
    {
        const int lane = t & 63;
        const int wv   = t >> 6;             // 0..7
        float w[12];
#pragma unroll
        for (int k = 0; k < 12; ++k) w[k] = W[k * 64 + lane];
        const float bb = bias[lane];

#pragma unroll
        for (int pp = 0; pp < 2; ++pp) {
            const int pi = wv + 8 * pp;      // point 0..15
            const int pg = chunk * PPB + pi; // batch-local point id
            const float xi0 = Xb[pg * 3 + 0], xi1 = Xb[pg * 3 + 1], xi2 = Xb[pg * 3 + 2];
            const float vi0 = Vb[pg * 3 + 0], vi1 = Vb[pg * 3 + 1], vi2 = Vb[pg * 3 + 2];
            const float base = bb + w[0] * xi0 + w[1] * xi1 + w[2] * xi2
                                  + w[6] * vi0 + w[7] * vi1 + w[8] * vi2;
            float acc = 0.0f;
#pragma unroll
            for (int n = 0; n < NNBR; ++n) {
                const float* f = nbf + (pi * NNBR + n) * 6;
                const float h = base + w[3]  * f[0] + w[4]  * f[1]
                                     + w[5]  * f[2] + w[9]  * f[3]
                                     + w[10] * f[4] + w[11] * f[5];
                acc += fmaxf(h, 0.0f);
            }
            out[(size_t)(b * NPTS + pg) * 64 + lane] = acc * (1.0f / 16.0f);
        }
    }
#undef STAGE
#undef SCAN1H
#undef SCAN2H
}

extern "C" void kernel_launch(void* const* d_in, const int* in_sizes, int n_in,
                              void* d_out, int out_size, void* d_ws, size_t ws_size,
                              hipStream_t stream) {
    const float* x0 = (const float*)d_in[0];   // (4, 12288)
    const float* v0 = (const float*)d_in[1];   // (4, 12288)
    const float* W  = (const float*)d_in[2];   // (12, 64)
    const float* bb = (const float*)d_in[3];   // (64,)
    float* out = (float*)d_out;

    // Single fused dispatch: 16-NN + MLP + mean + v0 copy.
    // 1024 blocks (4 batches x 256 chunks of 16 points), 512 threads.
    fused_kernel<<<1024, 512, 0, stream>>>(x0, v0, W, bb, out);
}